// Round 1
// 817.652 us; speedup vs baseline: 1.0995x; 1.0995x over previous
//
#include <hip/hip_runtime.h>
#include <cstdint>

typedef _Float16 f16;
typedef _Float16 f16x4 __attribute__((ext_vector_type(4)));
typedef _Float16 f16x8 __attribute__((ext_vector_type(8)));
typedef float f32x4 __attribute__((ext_vector_type(4)));

#define MFMA16(a, b, c) __builtin_amdgcn_mfma_f32_16x16x32_f16((a), (b), (c), 0, 0, 0)

// fast gelu: x * sigmoid(1.59576912x + 0.07135482x^3)  (tanh-gelu identity)
__device__ __forceinline__ float gelu_f(float x) {
    const float u = x * (1.5957691216f + 0.0713548163f * x * x);
    return x * __builtin_amdgcn_rcpf(1.0f + __expf(-u));
}

__device__ __forceinline__ void load_lds16(const void* g, void* l) {
    __builtin_amdgcn_global_load_lds(
        (const __attribute__((address_space(1))) void*)(uintptr_t)g,
        (__attribute__((address_space(3))) void*)(uint32_t)(uintptr_t)l,
        16, 0, 0);
}

// ---------------- prep: fp32 weights -> fp16 (with padding) ----------------
// W1p [512][832] (K pad 784->832, zeros), W2f[256][512], W3f[128][256],
// W4f[64][128], W5f[32][64], W6p[16][32] (rows 10..15 zero), Wrf[16][256]
__global__ void k_prep(const float* __restrict__ W1, const float* __restrict__ W2,
                       const float* __restrict__ W3, const float* __restrict__ W4,
                       const float* __restrict__ W5, const float* __restrict__ W6,
                       const float* __restrict__ Wr,
                       f16* __restrict__ W1p, f16* __restrict__ W2f, f16* __restrict__ W3f,
                       f16* __restrict__ W4f, f16* __restrict__ W5f, f16* __restrict__ W6p,
                       f16* __restrict__ Wrf) {
    int i = blockIdx.x * 256 + threadIdx.x;
    if (i < 425984) {
        int r = i / 832, c = i - r * 832;
        W1p[i] = (f16)(c < 784 ? W1[r * 784 + c] : 0.0f);
        return;
    }
    i -= 425984;
    if (i < 131072) { W2f[i] = (f16)W2[i]; return; }
    i -= 131072;
    if (i < 32768) { W3f[i] = (f16)W3[i]; return; }
    i -= 32768;
    if (i < 8192) { W4f[i] = (f16)W4[i]; return; }
    i -= 8192;
    if (i < 2048) { W5f[i] = (f16)W5[i]; return; }
    i -= 2048;
    if (i < 512) {
        int r = i >> 5, c = i & 31;
        W6p[i] = (f16)(r < 10 ? W6[r * 32 + c] : 0.0f);
        return;
    }
    i -= 512;
    if (i < 4096) { Wrf[i] = (f16)Wr[i]; return; }
}

// ---------------- GEMM1: H1 = gelu(X @ W1p^T + b1) ------------------------
// 2-phase double-buffered pipeline: stage(kt+1) issued BEFORE compute(kt) so
// HBM latency hides under frag-build+MFMA; one barrier per iteration.
// A: fp32 X staged via global_load_lds into [128][32]f32 panels, 8 slots/row,
//    XOR-swizzled (slot ^ (row&7)) -> 2-way bank access (free).
// B: f16 W1p staged into [256][32]h panels, 4 slots/row, slot ^ ((row>>1)&3).
// K-tail (k>=784): A source clamped to col 768 (garbage x W1p-zeros = 0).
__global__ __launch_bounds__(256, 2)
void k_gemm1(const float* __restrict__ A, const f16* __restrict__ Bw,
             const float* __restrict__ bias, f16* __restrict__ C) {
    __shared__ float As[2][128 * 32];   // 32 KB
    __shared__ f16   Bs[2][256 * 32];   // 32 KB
    const int tid = threadIdx.x;
    const int wave = tid >> 6, lane = tid & 63;
    const int nt = blockIdx.x & 1;           // 512 / 256
    const size_t mt = blockIdx.x >> 1;
    const size_t row0 = mt * 128;
    const int col0 = nt * 256;
    const int am = lane & 15, akg = lane >> 4;
    const int wm = (wave & 1) * 64, wn = (wave >> 1) * 128;
    const f32x4 zero4 = {0.f, 0.f, 0.f, 0.f};
    f32x4 acc[4][8];
#pragma unroll
    for (int i = 0; i < 4; ++i)
#pragma unroll
        for (int j = 0; j < 8; ++j) acc[i][j] = zero4;

    const int arow_l = lane >> 3, aps = lane & 7;   // A: 8 rows/inst, 8 slots/row
    const int brow_l = lane >> 2, bps = lane & 3;   // B: 16 rows/inst, 4 slots/row

    auto stage = [&](int kt, int buf) {
        const int kb = kt * 32;
#pragma unroll
        for (int i = 0; i < 4; ++i) {
            const int inst = wave * 4 + i;
            const int row = inst * 8 + arow_l;
            const int ls = aps ^ (row & 7);
            int c = kb + ls * 4;
            if (c > 780) c = 768;            // keep 16B load inside the row
            load_lds16(A + (row0 + row) * (size_t)784 + c, &As[buf][inst * 256]);
        }
#pragma unroll
        for (int i = 0; i < 4; ++i) {
            const int inst = wave * 4 + i;
            const int row = inst * 16 + brow_l;
            const int ls = bps ^ ((row >> 1) & 3);
            load_lds16(Bw + (size_t)(col0 + row) * 832 + kb + ls * 8, &Bs[buf][inst * 512]);
        }
    };

    stage(0, 0);
    __syncthreads();

    for (int kt = 0; kt < 26; ++kt) {
        const int cur = kt & 1;
        if (kt + 1 < 26) stage(kt + 1, cur ^ 1);   // prefetch next tile first
        f16x8 af[4];
#pragma unroll
        for (int i = 0; i < 4; ++i) {
            const int row = wm + i * 16 + am;
            const int rx = row & 7;
            const f32x4 lo = *(const f32x4*)&As[cur][row * 32 + (((akg << 1) ^ rx) << 2)];
            const f32x4 hi = *(const f32x4*)&As[cur][row * 32 + ((((akg << 1) | 1) ^ rx) << 2)];
            f16x8 v;
            v[0] = (f16)lo[0]; v[1] = (f16)lo[1]; v[2] = (f16)lo[2]; v[3] = (f16)lo[3];
            v[4] = (f16)hi[0]; v[5] = (f16)hi[1]; v[6] = (f16)hi[2]; v[7] = (f16)hi[3];
            af[i] = v;
        }
        f16x8 bf[8];
#pragma unroll
        for (int j = 0; j < 8; ++j) {
            const int row = wn + j * 16 + am;
            bf[j] = *(const f16x8*)&Bs[cur][row * 32 + ((akg ^ ((row >> 1) & 3)) << 3)];
        }
#pragma unroll
        for (int i = 0; i < 4; ++i)
#pragma unroll
            for (int j = 0; j < 8; ++j)
                acc[i][j] = MFMA16(bf[j], af[i], acc[i][j]);  // C^T frag
        __syncthreads();
    }
    // epilogue: lane holds row (am-based) x 4 consecutive cols
    const int cc = akg * 4;
#pragma unroll
    for (int i = 0; i < 4; ++i) {
        const size_t row = row0 + wm + i * 16 + am;
#pragma unroll
        for (int j = 0; j < 8; ++j) {
            const int col = col0 + wn + j * 16 + cc;
            const float4 b4 = *(const float4*)(bias + col);
            f16x4 v;
            v[0] = (f16)gelu_f(acc[i][j][0] + b4.x);
            v[1] = (f16)gelu_f(acc[i][j][1] + b4.y);
            v[2] = (f16)gelu_f(acc[i][j][2] + b4.z);
            v[3] = (f16)gelu_f(acc[i][j][3] + b4.w);
            *(f16x4*)(C + row * 512 + col) = v;
        }
    }
}

// ---------------- fused: GEMM2 + router + fc3 + L4 + L5 + L6 ---------------
// 128 rows/block, 512 threads (8 waves). GEMM2 (BK=64, dbuf, swizzled) writes
// gelu'd MID straight to LDS; single barrier; then wave-local tail phases
// (16 rows/wave) exactly as before. MID never touches HBM.
// LDS time-aliasing: gemm panels [0,98304) die at the epilogue; s_mid [0,67584)
// is written after the final barrier; tail buffers live at [67584,141312).
__global__ __launch_bounds__(512, 2)
void k_mid(const f16* __restrict__ H1v, const f16* __restrict__ W2f,
           const float* __restrict__ b2,
           const f16* __restrict__ W3f, const float* __restrict__ b3,
           const f16* __restrict__ W4f, const float* __restrict__ b4,
           const f16* __restrict__ W5f, const float* __restrict__ b5,
           const f16* __restrict__ W6p, const float* __restrict__ b6v,
           const f16* __restrict__ Wrf, const float* __restrict__ brv,
           float* __restrict__ OUT) {
    __shared__ __align__(16) char smem[141312];
    f16* Am = (f16*)smem;                   // [2][128*64] h = 32768 B (gemm only)
    f16* Bm = (f16*)(smem + 32768);         // [2][256*64] h = 65536 B (gemm only)
    f16* s_mid = (f16*)smem;                // [128][264] h = 67584 B (after gemm)
    float* s_pw = (float*)(smem + 67584);   // [128][20] f32 = 10240 B
    f16* s_mo = (f16*)(smem + 77824);       // [128][136] h = 34816 B
    f16* s_h4 = (f16*)(smem + 112640);      // [128][72] h = 18432 B
    f16* s_h5 = (f16*)(smem + 131072);      // [128][40] h = 10240 B
    const int tid = threadIdx.x, wave = tid >> 6, lane = tid & 63;
    const size_t row0 = (size_t)blockIdx.x * 128;
    const int am = lane & 15, akg = lane >> 4, ak = akg * 8;
    const int wm = (wave & 1) * 64, wn = (wave >> 1) * 64;
    const f32x4 zero4 = {0.f, 0.f, 0.f, 0.f};
    f32x4 acc[4][4];
#pragma unroll
    for (int i = 0; i < 4; ++i)
#pragma unroll
        for (int j = 0; j < 4; ++j) acc[i][j] = zero4;

    auto stage = [&](int kt, int buf) {
        const int kb = kt * 64;
#pragma unroll
        for (int t = 0; t < 2; ++t) {        // A: 128 rows x 64h, 8 slots/row
            const int idx = t * 512 + tid;
            const int row = idx >> 3;
            const int ls = (idx & 7) ^ (row & 7);
            load_lds16(H1v + (row0 + row) * 512 + kb + ls * 8,
                       Am + buf * 8192 + (t * 512 + wave * 64) * 8);
        }
#pragma unroll
        for (int t = 0; t < 4; ++t) {        // B: 256 rows x 64h
            const int idx = t * 512 + tid;
            const int row = idx >> 3;
            const int ls = (idx & 7) ^ (row & 7);
            load_lds16(W2f + (size_t)row * 512 + kb + ls * 8,
                       Bm + buf * 16384 + (t * 512 + wave * 64) * 8);
        }
    };

    stage(0, 0);
    __syncthreads();
    for (int kt = 0; kt < 8; ++kt) {
        const int cur = kt & 1;
        if (kt + 1 < 8) stage(kt + 1, cur ^ 1);
#pragma unroll
        for (int ks = 0; ks < 2; ++ks) {
            f16x8 af[4], bf[4];
#pragma unroll
            for (int i = 0; i < 4; ++i) {
                const int row = wm + i * 16 + am;
                af[i] = *(const f16x8*)&Am[cur * 8192 + row * 64 +
                                           ((((ks << 2) | akg) ^ (row & 7)) << 3)];
            }
#pragma unroll
            for (int j = 0; j < 4; ++j) {
                const int row = wn + j * 16 + am;
                bf[j] = *(const f16x8*)&Bm[cur * 16384 + row * 64 +
                                           ((((ks << 2) | akg) ^ (row & 7)) << 3)];
            }
#pragma unroll
            for (int i = 0; i < 4; ++i)
#pragma unroll
                for (int j = 0; j < 4; ++j)
                    acc[i][j] = MFMA16(bf[j], af[i], acc[i][j]);
        }
        __syncthreads();
    }
    // epilogue: gelu(acc + b2) -> s_mid (gemm panels are dead past this point)
    {
        const int cc = akg * 4;
#pragma unroll
        for (int i = 0; i < 4; ++i) {
            const int row = wm + i * 16 + am;
#pragma unroll
            for (int j = 0; j < 4; ++j) {
                const int col = wn + j * 16 + cc;
                const float4 bb = *(const float4*)(b2 + col);
                f16x4 v;
                v[0] = (f16)gelu_f(acc[i][j][0] + bb.x);
                v[1] = (f16)gelu_f(acc[i][j][1] + bb.y);
                v[2] = (f16)gelu_f(acc[i][j][2] + bb.z);
                v[3] = (f16)gelu_f(acc[i][j][3] + bb.w);
                *(f16x4*)&s_mid[row * 264 + col] = v;
            }
        }
    }
    __syncthreads();

    // ---- tail: every phase wave-local (16 rows per wave), no more barriers
    const int wr = wave * 16;
    const int crow = wr + akg * 4;

    // phase 2: router logits + softmax across 16 lanes
    {
        f32x4 lacc = zero4;
#pragma unroll
        for (int ks = 0; ks < 8; ++ks) {
            f16x8 a = *(const f16x8*)(s_mid + (wr + am) * 264 + ks * 32 + ak);
            f16x8 b = *(const f16x8*)(Wrf + am * 256 + ks * 32 + ak);
            lacc = MFMA16(a, b, lacc);
        }
        const float brn = brv[am];
#pragma unroll
        for (int r = 0; r < 4; ++r) {
            float l = lacc[r] + brn;
            float mx = l;
#pragma unroll
            for (int m = 1; m <= 8; m <<= 1) mx = fmaxf(mx, __shfl_xor(mx, m));
            const float e = __expf(l - mx);
            float s = e;
#pragma unroll
            for (int m = 1; m <= 8; m <<= 1) s += __shfl_xor(s, m);
            const float p = e / s;
            float sg = p;
            sg += __shfl_xor(sg, 4);
            sg += __shfl_xor(sg, 8);
            s_pw[(crow + r) * 20 + am] = p;
            if (am < 4) s_pw[(crow + r) * 20 + 16 + am] = sg;
        }
    }

    // phase 3: grouped fc3 + pathway-weighted combine + gelu -> s_mo
    {
        f16x8 a3[4][2];
#pragma unroll
        for (int g = 0; g < 4; ++g)
#pragma unroll
            for (int kh = 0; kh < 2; ++kh)
                a3[g][kh] = *(const f16x8*)(s_mid + (wr + am) * 264 + g * 64 + kh * 32 + ak);
#pragma unroll
        for (int o = 0; o < 4; ++o) {
            float pwv[4][4], sgl[4];
#pragma unroll
            for (int r = 0; r < 4; ++r) {
                sgl[r] = s_pw[(crow + r) * 20 + 16 + o];
#pragma unroll
                for (int g = 0; g < 4; ++g)
                    pwv[g][r] = s_pw[(crow + r) * 20 + g * 4 + o];
            }
#pragma unroll
            for (int ctl = 0; ctl < 2; ++ctl) {
                const int ct = o * 2 + ctl;
                const int col = ct * 16 + am;
                const float bias = b3[col];
                f32x4 oacc;
#pragma unroll
                for (int r = 0; r < 4; ++r) oacc[r] = bias * sgl[r];
#pragma unroll
                for (int g = 0; g < 4; ++g) {
                    f32x4 t = zero4;
                    t = MFMA16(a3[g][0], *(const f16x8*)(W3f + (size_t)col * 256 + g * 64 + ak), t);
                    t = MFMA16(a3[g][1], *(const f16x8*)(W3f + (size_t)col * 256 + g * 64 + 32 + ak), t);
#pragma unroll
                    for (int r = 0; r < 4; ++r) oacc[r] += pwv[g][r] * t[r];
                }
#pragma unroll
                for (int r = 0; r < 4; ++r)
                    s_mo[(crow + r) * 136 + col] = (f16)gelu_f(oacc[r]);
            }
        }
    }

    // phase 4: L4
    {
        f16x8 a4[4];
#pragma unroll
        for (int ks = 0; ks < 4; ++ks)
            a4[ks] = *(const f16x8*)(s_mo + (wr + am) * 136 + ks * 32 + ak);
#pragma unroll
        for (int ct = 0; ct < 4; ++ct) {
            const int col = ct * 16 + am;
            f32x4 acc4 = zero4;
#pragma unroll
            for (int ks = 0; ks < 4; ++ks)
                acc4 = MFMA16(a4[ks], *(const f16x8*)(W4f + (size_t)col * 128 + ks * 32 + ak), acc4);
            const float bias = b4[col];
#pragma unroll
            for (int r = 0; r < 4; ++r)
                s_h4[(crow + r) * 72 + col] = (f16)gelu_f(acc4[r] + bias);
        }
    }

    // phase 5: L5
    {
        f16x8 a5[2];
#pragma unroll
        for (int ks = 0; ks < 2; ++ks)
            a5[ks] = *(const f16x8*)(s_h4 + (wr + am) * 72 + ks * 32 + ak);
#pragma unroll
        for (int ct = 0; ct < 2; ++ct) {
            const int col = ct * 16 + am;
            f32x4 acc5 = zero4;
#pragma unroll
            for (int ks = 0; ks < 2; ++ks)
                acc5 = MFMA16(a5[ks], *(const f16x8*)(W5f + (size_t)col * 64 + ks * 32 + ak), acc5);
            const float bias = b5[col];
#pragma unroll
            for (int r = 0; r < 4; ++r)
                s_h5[(crow + r) * 40 + col] = (f16)gelu_f(acc5[r] + bias);
        }
    }

    // phase 6: L6
    {
        f16x8 a6 = *(const f16x8*)(s_h5 + (wr + am) * 40 + ak);
        f16x8 bw = *(const f16x8*)(W6p + am * 32 + ak);
        f32x4 acc6 = MFMA16(a6, bw, zero4);
        if (am < 10) {
            const float bb = b6v[am];
#pragma unroll
            for (int r = 0; r < 4; ++r)
                OUT[(row0 + crow + r) * 10 + am] = acc6[r] + bb;
        }
    }
}

extern "C" void kernel_launch(void* const* d_in, const int* in_sizes, int n_in,
                              void* d_out, int out_size, void* d_ws, size_t ws_size,
                              hipStream_t stream) {
    const float* x  = (const float*)d_in[0];
    const float* W1 = (const float*)d_in[1];
    const float* b1 = (const float*)d_in[2];
    const float* W2 = (const float*)d_in[3];
    const float* b2 = (const float*)d_in[4];
    const float* W3 = (const float*)d_in[5];
    const float* b3 = (const float*)d_in[6];
    const float* W4 = (const float*)d_in[7];
    const float* b4 = (const float*)d_in[8];
    const float* W5 = (const float*)d_in[9];
    const float* b5 = (const float*)d_in[10];
    const float* W6 = (const float*)d_in[11];
    const float* b6 = (const float*)d_in[12];
    const float* Wr = (const float*)d_in[13];
    const float* br = (const float*)d_in[14];
    float* out = (float*)d_out;

    const int M = in_sizes[0] / 784;    // 131072

    char* ws = (char*)d_ws;
    f16* W1p = (f16*)ws; ws += 512 * 832 * 2;
    f16* W2f = (f16*)ws; ws += 256 * 512 * 2;
    f16* W3f = (f16*)ws; ws += 128 * 256 * 2;
    f16* W4f = (f16*)ws; ws += 64 * 128 * 2;
    f16* W5f = (f16*)ws; ws += 32 * 64 * 2;
    f16* W6p = (f16*)ws; ws += 16 * 32 * 2;
    f16* Wrf = (f16*)ws; ws += 16 * 256 * 2;
    f16* H1  = (f16*)ws; ws += (size_t)M * 512 * 2; // 134 MB

    k_prep<<<2362, 256, 0, stream>>>(W1, W2, W3, W4, W5, W6, Wr,
                                     W1p, W2f, W3f, W4f, W5f, W6p, Wrf);
    k_gemm1<<<(M / 128) * 2, 256, 0, stream>>>(x, W1p, b1, H1);
    k_mid<<<M / 128, 512, 0, stream>>>(H1, W2f, b2, W3f, b3, W4f, b4, W5f, b5,
                                       W6p, b6, Wrf, br, out);
}

// Round 2
// 799.626 us; speedup vs baseline: 1.1243x; 1.0225x over previous
//
#include <hip/hip_runtime.h>
#include <cstdint>

typedef _Float16 f16;
typedef _Float16 f16x4 __attribute__((ext_vector_type(4)));
typedef _Float16 f16x8 __attribute__((ext_vector_type(8)));
typedef float f32x4 __attribute__((ext_vector_type(4)));

#define MFMA16(a, b, c) __builtin_amdgcn_mfma_f32_16x16x32_f16((a), (b), (c), 0, 0, 0)
#define SBAR() __builtin_amdgcn_s_barrier()
#define SCHEDB() __builtin_amdgcn_sched_barrier(0)

// fast gelu: x * sigmoid(1.59576912x + 0.07135482x^3)  (tanh-gelu identity)
__device__ __forceinline__ float gelu_f(float x) {
    const float u = x * (1.5957691216f + 0.0713548163f * x * x);
    return x * __builtin_amdgcn_rcpf(1.0f + __expf(-u));
}

__device__ __forceinline__ void load_lds16(const void* g, void* l) {
    __builtin_amdgcn_global_load_lds(
        (const __attribute__((address_space(1))) void*)(uintptr_t)g,
        (__attribute__((address_space(3))) void*)(uint32_t)(uintptr_t)l,
        16, 0, 0);
}

// ---------------- prep: fp32 weights -> fp16 (with padding) ----------------
// W1p [512][832] (K pad 784->832, zeros), W2f[256][512], W3f[128][256],
// W4f[64][128], W5f[32][64], W6p[16][32] (rows 10..15 zero), Wrf[16][256]
__global__ void k_prep(const float* __restrict__ W1, const float* __restrict__ W2,
                       const float* __restrict__ W3, const float* __restrict__ W4,
                       const float* __restrict__ W5, const float* __restrict__ W6,
                       const float* __restrict__ Wr,
                       f16* __restrict__ W1p, f16* __restrict__ W2f, f16* __restrict__ W3f,
                       f16* __restrict__ W4f, f16* __restrict__ W5f, f16* __restrict__ W6p,
                       f16* __restrict__ Wrf) {
    int i = blockIdx.x * 256 + threadIdx.x;
    if (i < 425984) {
        int r = i / 832, c = i - r * 832;
        W1p[i] = (f16)(c < 784 ? W1[r * 784 + c] : 0.0f);
        return;
    }
    i -= 425984;
    if (i < 131072) { W2f[i] = (f16)W2[i]; return; }
    i -= 131072;
    if (i < 32768) { W3f[i] = (f16)W3[i]; return; }
    i -= 32768;
    if (i < 8192) { W4f[i] = (f16)W4[i]; return; }
    i -= 8192;
    if (i < 2048) { W5f[i] = (f16)W5[i]; return; }
    i -= 2048;
    if (i < 512) {
        int r = i >> 5, c = i & 31;
        W6p[i] = (f16)(r < 10 ? W6[r * 32 + c] : 0.0f);
        return;
    }
    i -= 512;
    if (i < 4096) { Wrf[i] = (f16)Wr[i]; return; }
}

// ---------------- GEMM1: H1 = gelu(X @ W1p^T + b1) ------------------------
// Double-buffered pipeline with COUNTED vmcnt + raw barriers: tile t+1's 8
// global_load_lds stay in flight across the barrier (full-iteration latency
// budget) instead of being drained by __syncthreads' vmcnt(0).
// A: fp32 X staged into [128][32]f32 panels, 8 slots/row, slot ^ (row&7).
// B: f16 W1p staged into [256][32]h panels, 4 slots/row, slot ^ ((row>>1)&3).
// K-tail (k>=784): A source clamped (garbage x W1p-zeros = 0).
__global__ __launch_bounds__(256, 2)
void k_gemm1(const float* __restrict__ A, const f16* __restrict__ Bw,
             const float* __restrict__ bias, f16* __restrict__ C) {
    __shared__ float As[2][128 * 32];   // 32 KB
    __shared__ f16   Bs[2][256 * 32];   // 32 KB
    const int tid = threadIdx.x;
    const int wave = tid >> 6, lane = tid & 63;
    const int nt = blockIdx.x & 1;           // 512 / 256
    const size_t mt = blockIdx.x >> 1;
    const size_t row0 = mt * 128;
    const int col0 = nt * 256;
    const int am = lane & 15, akg = lane >> 4;
    const int wm = (wave & 1) * 64, wn = (wave >> 1) * 128;
    const f32x4 zero4 = {0.f, 0.f, 0.f, 0.f};
    f32x4 acc[4][8];
#pragma unroll
    for (int i = 0; i < 4; ++i)
#pragma unroll
        for (int j = 0; j < 8; ++j) acc[i][j] = zero4;

    const int arow_l = lane >> 3, aps = lane & 7;   // A: 8 rows/inst, 8 slots/row
    const int brow_l = lane >> 2, bps = lane & 3;   // B: 16 rows/inst, 4 slots/row

    auto stage = [&](int kt, int buf) {
        const int kb = kt * 32;
#pragma unroll
        for (int i = 0; i < 4; ++i) {
            const int inst = wave * 4 + i;
            const int row = inst * 8 + arow_l;
            const int ls = aps ^ (row & 7);
            int c = kb + ls * 4;
            if (c > 780) c = 768;            // keep 16B load inside the row
            load_lds16(A + (row0 + row) * (size_t)784 + c, &As[buf][inst * 256]);
        }
#pragma unroll
        for (int i = 0; i < 4; ++i) {
            const int inst = wave * 4 + i;
            const int row = inst * 16 + brow_l;
            const int ls = bps ^ ((row >> 1) & 3);
            load_lds16(Bw + (size_t)(col0 + row) * 832 + kb + ls * 8, &Bs[buf][inst * 512]);
        }
    };

    stage(0, 0);                              // 8 loads in flight

    for (int kt = 0; kt < 26; ++kt) {
        const int cur = kt & 1;
        if (kt + 1 < 26) {
            stage(kt + 1, cur ^ 1);           // 16 in flight
            asm volatile("s_waitcnt vmcnt(8)" ::: "memory");  // tile kt done
        } else {
            asm volatile("s_waitcnt vmcnt(0)" ::: "memory");
        }
        SBAR();                               // all waves see tile kt in LDS
        SCHEDB();
        f16x8 af[4];
#pragma unroll
        for (int i = 0; i < 4; ++i) {
            const int row = wm + i * 16 + am;
            const int rx = row & 7;
            const f32x4 lo = *(const f32x4*)&As[cur][row * 32 + (((akg << 1) ^ rx) << 2)];
            const f32x4 hi = *(const f32x4*)&As[cur][row * 32 + ((((akg << 1) | 1) ^ rx) << 2)];
            f16x8 v;
            v[0] = (f16)lo[0]; v[1] = (f16)lo[1]; v[2] = (f16)lo[2]; v[3] = (f16)lo[3];
            v[4] = (f16)hi[0]; v[5] = (f16)hi[1]; v[6] = (f16)hi[2]; v[7] = (f16)hi[3];
            af[i] = v;
        }
        f16x8 bf[8];
#pragma unroll
        for (int j = 0; j < 8; ++j) {
            const int row = wn + j * 16 + am;
            bf[j] = *(const f16x8*)&Bs[cur][row * 32 + ((akg ^ ((row >> 1) & 3)) << 3)];
        }
#pragma unroll
        for (int i = 0; i < 4; ++i)
#pragma unroll
            for (int j = 0; j < 8; ++j)
                acc[i][j] = MFMA16(bf[j], af[i], acc[i][j]);  // C^T frag
        SCHEDB();
        if (kt + 1 < 26) SBAR();              // buf safe to overwrite next iter
    }
    // epilogue: lane holds row (am-based) x 4 consecutive cols
    const int cc = akg * 4;
#pragma unroll
    for (int i = 0; i < 4; ++i) {
        const size_t row = row0 + wm + i * 16 + am;
#pragma unroll
        for (int j = 0; j < 8; ++j) {
            const int col = col0 + wn + j * 16 + cc;
            const float4 b4 = *(const float4*)(bias + col);
            f16x4 v;
            v[0] = (f16)gelu_f(acc[i][j][0] + b4.x);
            v[1] = (f16)gelu_f(acc[i][j][1] + b4.y);
            v[2] = (f16)gelu_f(acc[i][j][2] + b4.z);
            v[3] = (f16)gelu_f(acc[i][j][3] + b4.w);
            *(f16x4*)(C + row * 512 + col) = v;
        }
    }
}

// ---------------- fused: GEMM2 + router + fc3 + L4 + L5 + L6 ---------------
// 128 rows/block, 512 threads (8 waves). GEMM2 (BK=64, dbuf, counted-vmcnt
// pipeline) writes gelu'd MID straight to LDS; single barrier; then wave-local
// tail phases (16 rows/wave). MID never touches HBM.
__global__ __launch_bounds__(512, 2)
void k_mid(const f16* __restrict__ H1v, const f16* __restrict__ W2f,
           const float* __restrict__ b2,
           const f16* __restrict__ W3f, const float* __restrict__ b3,
           const f16* __restrict__ W4f, const float* __restrict__ b4,
           const f16* __restrict__ W5f, const float* __restrict__ b5,
           const f16* __restrict__ W6p, const float* __restrict__ b6v,
           const f16* __restrict__ Wrf, const float* __restrict__ brv,
           float* __restrict__ OUT) {
    __shared__ __align__(16) char smem[141312];
    f16* Am = (f16*)smem;                   // [2][128*64] h = 32768 B (gemm only)
    f16* Bm = (f16*)(smem + 32768);         // [2][256*64] h = 65536 B (gemm only)
    f16* s_mid = (f16*)smem;                // [128][264] h = 67584 B (after gemm)
    float* s_pw = (float*)(smem + 67584);   // [128][20] f32 = 10240 B
    f16* s_mo = (f16*)(smem + 77824);       // [128][136] h = 34816 B
    f16* s_h4 = (f16*)(smem + 112640);      // [128][72] h = 18432 B
    f16* s_h5 = (f16*)(smem + 131072);      // [128][40] h = 10240 B
    const int tid = threadIdx.x, wave = tid >> 6, lane = tid & 63;
    const size_t row0 = (size_t)blockIdx.x * 128;
    const int am = lane & 15, akg = lane >> 4, ak = akg * 8;
    const int wm = (wave & 1) * 64, wn = (wave >> 1) * 64;
    const f32x4 zero4 = {0.f, 0.f, 0.f, 0.f};
    f32x4 acc[4][4];
#pragma unroll
    for (int i = 0; i < 4; ++i)
#pragma unroll
        for (int j = 0; j < 4; ++j) acc[i][j] = zero4;

    auto stage = [&](int kt, int buf) {
        const int kb = kt * 64;
#pragma unroll
        for (int t = 0; t < 2; ++t) {        // A: 128 rows x 64h, 8 slots/row
            const int idx = t * 512 + tid;
            const int row = idx >> 3;
            const int ls = (idx & 7) ^ (row & 7);
            load_lds16(H1v + (row0 + row) * 512 + kb + ls * 8,
                       Am + buf * 8192 + (t * 512 + wave * 64) * 8);
        }
#pragma unroll
        for (int t = 0; t < 4; ++t) {        // B: 256 rows x 64h
            const int idx = t * 512 + tid;
            const int row = idx >> 3;
            const int ls = (idx & 7) ^ (row & 7);
            load_lds16(W2f + (size_t)row * 512 + kb + ls * 8,
                       Bm + buf * 16384 + (t * 512 + wave * 64) * 8);
        }
    };

    stage(0, 0);                              // 6 loads in flight
    for (int kt = 0; kt < 8; ++kt) {
        const int cur = kt & 1;
        if (kt + 1 < 8) {
            stage(kt + 1, cur ^ 1);           // 12 in flight
            asm volatile("s_waitcnt vmcnt(6)" ::: "memory");  // tile kt done
        } else {
            asm volatile("s_waitcnt vmcnt(0)" ::: "memory");
        }
        SBAR();
        SCHEDB();
#pragma unroll
        for (int ks = 0; ks < 2; ++ks) {
            f16x8 af[4], bf[4];
#pragma unroll
            for (int i = 0; i < 4; ++i) {
                const int row = wm + i * 16 + am;
                af[i] = *(const f16x8*)&Am[cur * 8192 + row * 64 +
                                           ((((ks << 2) | akg) ^ (row & 7)) << 3)];
            }
#pragma unroll
            for (int j = 0; j < 4; ++j) {
                const int row = wn + j * 16 + am;
                bf[j] = *(const f16x8*)&Bm[cur * 16384 + row * 64 +
                                           ((((ks << 2) | akg) ^ (row & 7)) << 3)];
            }
#pragma unroll
            for (int i = 0; i < 4; ++i)
#pragma unroll
                for (int j = 0; j < 4; ++j)
                    acc[i][j] = MFMA16(bf[j], af[i], acc[i][j]);
        }
        SCHEDB();
        asm volatile("s_waitcnt lgkmcnt(0)" ::: "memory");  // reads consumed
        SBAR();                               // buf safe to overwrite
    }
    // epilogue: gelu(acc + b2) -> s_mid (gemm panels are dead past this point;
    // final-iteration trailing SBAR above synced all waves)
    {
        const int cc = akg * 4;
#pragma unroll
        for (int i = 0; i < 4; ++i) {
            const int row = wm + i * 16 + am;
#pragma unroll
            for (int j = 0; j < 4; ++j) {
                const int col = wn + j * 16 + cc;
                const float4 bb = *(const float4*)(b2 + col);
                f16x4 v;
                v[0] = (f16)gelu_f(acc[i][j][0] + bb.x);
                v[1] = (f16)gelu_f(acc[i][j][1] + bb.y);
                v[2] = (f16)gelu_f(acc[i][j][2] + bb.z);
                v[3] = (f16)gelu_f(acc[i][j][3] + bb.w);
                *(f16x4*)&s_mid[row * 264 + col] = v;
            }
        }
    }
    __syncthreads();

    // ---- tail: every phase wave-local (16 rows per wave), no more barriers
    const int wr = wave * 16;
    const int crow = wr + akg * 4;

    // phase 2: router logits + softmax across 16 lanes
    {
        f32x4 lacc = zero4;
#pragma unroll
        for (int ks = 0; ks < 8; ++ks) {
            f16x8 a = *(const f16x8*)(s_mid + (wr + am) * 264 + ks * 32 + ak);
            f16x8 b = *(const f16x8*)(Wrf + am * 256 + ks * 32 + ak);
            lacc = MFMA16(a, b, lacc);
        }
        const float brn = brv[am];
#pragma unroll
        for (int r = 0; r < 4; ++r) {
            float l = lacc[r] + brn;
            float mx = l;
#pragma unroll
            for (int m = 1; m <= 8; m <<= 1) mx = fmaxf(mx, __shfl_xor(mx, m));
            const float e = __expf(l - mx);
            float s = e;
#pragma unroll
            for (int m = 1; m <= 8; m <<= 1) s += __shfl_xor(s, m);
            const float p = e / s;
            float sg = p;
            sg += __shfl_xor(sg, 4);
            sg += __shfl_xor(sg, 8);
            s_pw[(crow + r) * 20 + am] = p;
            if (am < 4) s_pw[(crow + r) * 20 + 16 + am] = sg;
        }
    }

    // phase 3: grouped fc3 + pathway-weighted combine + gelu -> s_mo
    {
        f16x8 a3[4][2];
#pragma unroll
        for (int g = 0; g < 4; ++g)
#pragma unroll
            for (int kh = 0; kh < 2; ++kh)
                a3[g][kh] = *(const f16x8*)(s_mid + (wr + am) * 264 + g * 64 + kh * 32 + ak);
#pragma unroll
        for (int o = 0; o < 4; ++o) {
            float pwv[4][4], sgl[4];
#pragma unroll
            for (int r = 0; r < 4; ++r) {
                sgl[r] = s_pw[(crow + r) * 20 + 16 + o];
#pragma unroll
                for (int g = 0; g < 4; ++g)
                    pwv[g][r] = s_pw[(crow + r) * 20 + g * 4 + o];
            }
#pragma unroll
            for (int ctl = 0; ctl < 2; ++ctl) {
                const int ct = o * 2 + ctl;
                const int col = ct * 16 + am;
                const float bias = b3[col];
                f32x4 oacc;
#pragma unroll
                for (int r = 0; r < 4; ++r) oacc[r] = bias * sgl[r];
#pragma unroll
                for (int g = 0; g < 4; ++g) {
                    f32x4 t = zero4;
                    t = MFMA16(a3[g][0], *(const f16x8*)(W3f + (size_t)col * 256 + g * 64 + ak), t);
                    t = MFMA16(a3[g][1], *(const f16x8*)(W3f + (size_t)col * 256 + g * 64 + 32 + ak), t);
#pragma unroll
                    for (int r = 0; r < 4; ++r) oacc[r] += pwv[g][r] * t[r];
                }
#pragma unroll
                for (int r = 0; r < 4; ++r)
                    s_mo[(crow + r) * 136 + col] = (f16)gelu_f(oacc[r]);
            }
        }
    }

    // phase 4: L4
    {
        f16x8 a4[4];
#pragma unroll
        for (int ks = 0; ks < 4; ++ks)
            a4[ks] = *(const f16x8*)(s_mo + (wr + am) * 136 + ks * 32 + ak);
#pragma unroll
        for (int ct = 0; ct < 4; ++ct) {
            const int col = ct * 16 + am;
            f32x4 acc4 = zero4;
#pragma unroll
            for (int ks = 0; ks < 4; ++ks)
                acc4 = MFMA16(a4[ks], *(const f16x8*)(W4f + (size_t)col * 128 + ks * 32 + ak), acc4);
            const float bias = b4[col];
#pragma unroll
            for (int r = 0; r < 4; ++r)
                s_h4[(crow + r) * 72 + col] = (f16)gelu_f(acc4[r] + bias);
        }
    }

    // phase 5: L5
    {
        f16x8 a5[2];
#pragma unroll
        for (int ks = 0; ks < 2; ++ks)
            a5[ks] = *(const f16x8*)(s_h4 + (wr + am) * 72 + ks * 32 + ak);
#pragma unroll
        for (int ct = 0; ct < 2; ++ct) {
            const int col = ct * 16 + am;
            f32x4 acc5 = zero4;
#pragma unroll
            for (int ks = 0; ks < 2; ++ks)
                acc5 = MFMA16(a5[ks], *(const f16x8*)(W5f + (size_t)col * 64 + ks * 32 + ak), acc5);
            const float bias = b5[col];
#pragma unroll
            for (int r = 0; r < 4; ++r)
                s_h5[(crow + r) * 40 + col] = (f16)gelu_f(acc5[r] + bias);
        }
    }

    // phase 6: L6
    {
        f16x8 a6 = *(const f16x8*)(s_h5 + (wr + am) * 40 + ak);
        f16x8 bw = *(const f16x8*)(W6p + am * 32 + ak);
        f32x4 acc6 = MFMA16(a6, bw, zero4);
        if (am < 10) {
            const float bb = b6v[am];
#pragma unroll
            for (int r = 0; r < 4; ++r)
                OUT[(row0 + crow + r) * 10 + am] = acc6[r] + bb;
        }
    }
}

extern "C" void kernel_launch(void* const* d_in, const int* in_sizes, int n_in,
                              void* d_out, int out_size, void* d_ws, size_t ws_size,
                              hipStream_t stream) {
    const float* x  = (const float*)d_in[0];
    const float* W1 = (const float*)d_in[1];
    const float* b1 = (const float*)d_in[2];
    const float* W2 = (const float*)d_in[3];
    const float* b2 = (const float*)d_in[4];
    const float* W3 = (const float*)d_in[5];
    const float* b3 = (const float*)d_in[6];
    const float* W4 = (const float*)d_in[7];
    const float* b4 = (const float*)d_in[8];
    const float* W5 = (const float*)d_in[9];
    const float* b5 = (const float*)d_in[10];
    const float* W6 = (const float*)d_in[11];
    const float* b6 = (const float*)d_in[12];
    const float* Wr = (const float*)d_in[13];
    const float* br = (const float*)d_in[14];
    float* out = (float*)d_out;

    const int M = in_sizes[0] / 784;    // 131072

    char* ws = (char*)d_ws;
    f16* W1p = (f16*)ws; ws += 512 * 832 * 2;
    f16* W2f = (f16*)ws; ws += 256 * 512 * 2;
    f16* W3f = (f16*)ws; ws += 128 * 256 * 2;
    f16* W4f = (f16*)ws; ws += 64 * 128 * 2;
    f16* W5f = (f16*)ws; ws += 32 * 64 * 2;
    f16* W6p = (f16*)ws; ws += 16 * 32 * 2;
    f16* Wrf = (f16*)ws; ws += 16 * 256 * 2;
    f16* H1  = (f16*)ws; ws += (size_t)M * 512 * 2; // 134 MB

    k_prep<<<2362, 256, 0, stream>>>(W1, W2, W3, W4, W5, W6, Wr,
                                     W1p, W2f, W3f, W4f, W5f, W6p, Wrf);
    k_gemm1<<<(M / 128) * 2, 256, 0, stream>>>(x, W1p, b1, H1);
    k_mid<<<M / 128, 512, 0, stream>>>(H1, W2f, b2, W3f, b3, W4f, b4, W5f, b5,
                                       W6p, b6, Wrf, br, out);
}